// Round 1
// baseline (9967.631 us; speedup 1.0000x reference)
//
#include <hip/hip_runtime.h>

#define B_ 64
#define T_ 512
#define D_ 32
#define U_ 512
#define SIGD 1056
#define G_ 64   // scan workgroups (all co-resident: 64 blocks << 256 CUs)

typedef _Float16 half8 __attribute__((ext_vector_type(8)));
typedef float f32x4 __attribute__((ext_vector_type(4)));
typedef unsigned short ushort_t;
typedef unsigned int uint_t;

// ---- workspace layout (bytes) ----  total ~143 MB
#define SIG_OFF   0ull            // fp16 norm_sigs  [b*512+t][1056]           69,206,016
#define F_OFF     69206016ull     // fp32 f_all      [t][b][u]                 67,108,864
#define A_OFF     136314880ull    // fp32 a = S1[t-1]+.5dx   [b][t][i]          4,194,304
#define DX_OFF    140509184ull    // fp32 dx                 [b][t][i]          4,194,304
#define X16_OFF   144703488ull    // fp16 x          [t][b][i]                  2,097,152
#define R16_OFF   146800640ull    // fp16 [R;Wi]     [k=544][n=1536]            1,671,168
#define WF16_OFF  148471808ull    // fp16 Wf         [k=1056][n=512]            1,081,344
#define HB_OFF    149553152ull    // fp16 h double buffer: 2 x [64][512]          131,072
#define CNT_OFF   149684224ull    // u32 arrival counters [512]                     2,048

// ============ K0: dx / a / x16 precompute + zero h/counters ============
__global__ __launch_bounds__(256) void k_prep(const float* __restrict__ x,
                                              _Float16* x16, float* a_buf, float* dx_buf,
                                              uint_t* hb, uint_t* cnt) {
  int b = blockIdx.x;
  int tid = threadIdx.x;
  if (b == 64) {  // zero both h buffers (32768 u32) + 512 counters
    for (int i = tid; i < 32768 + 512; i += 256) {
      if (i < 32768) hb[i] = 0u;
      else cnt[i - 32768] = 0u;
    }
    return;
  }
  if (tid >= 32) return;
  int i = tid;
  float xprev = x[(b * T_) * D_ + i];
  x16[(0 * B_ + b) * D_ + i] = (_Float16)xprev;
  a_buf[(b * T_) * D_ + i] = 0.f;
  dx_buf[(b * T_) * D_ + i] = 0.f;
  float S1 = 0.f;
  for (int t = 1; t < T_; ++t) {
    float xv = x[(b * T_ + t) * D_ + i];
    float dx = xv - xprev;
    float a = S1 + 0.5f * dx;   // S1 before this increment, + half-dx term
    S1 += dx;
    a_buf[(b * T_ + t) * D_ + i] = a;
    dx_buf[(b * T_ + t) * D_ + i] = dx;
    x16[(t * B_ + b) * D_ + i] = (_Float16)xv;
    xprev = xv;
  }
}

// ============ K0b: weight fp16 conversion ============
// R16t = concat(recurrent[512][1536], input[32][1536]) flat; Wf16 = forget flat.
__global__ __launch_bounds__(256) void k_weights(const float* __restrict__ rk,
                                                 const float* __restrict__ ik,
                                                 const float* __restrict__ fk,
                                                 _Float16* R16t, _Float16* Wf16) {
  int e = (blockIdx.x * 256 + threadIdx.x) * 4;
  if (e < 835584) {
    const float* src = (e < 786432) ? (rk + e) : (ik + (e - 786432));
#pragma unroll
    for (int j = 0; j < 4; ++j) R16t[e + j] = (_Float16)src[j];
  } else {
    int e2 = e - 835584;  // < 540672
#pragma unroll
    for (int j = 0; j < 4; ++j) Wf16[e2 + j] = (_Float16)fk[e2 + j];
  }
}

// ============ K1: signature stream -> normalized fp16 sig matrix ============
// thread (i,j) cumsums S2[i][j] += a[t][i]*dx[t][j]; row t scaled by 1/t.
__global__ __launch_bounds__(1024) void k_sig(const float* __restrict__ a_buf,
                                              const float* __restrict__ dx_buf,
                                              _Float16* __restrict__ sig) {
  int b = blockIdx.x;
  int tid = threadIdx.x;
  int i = tid >> 5, j = tid & 31;
  __shared__ float a_ch[32][32];
  __shared__ float dx_ch[32][32];
  float S2 = 0.f;
  for (int t0 = 0; t0 < T_; t0 += 32) {
    a_ch[i][j]  = a_buf[(b * T_ + t0 + i) * D_ + j];
    dx_ch[i][j] = dx_buf[(b * T_ + t0 + i) * D_ + j];
    __syncthreads();
#pragma unroll 4
    for (int tt = 0; tt < 32; ++tt) {
      int t = t0 + tt;
      S2 += a_ch[tt][i] * dx_ch[tt][j];
      float inv = (t == 0) ? 0.f : (1.0f / (float)t);
      int row = b * T_ + t;
      sig[row * SIGD + 32 + i * 32 + j] = (_Float16)(S2 * inv);
      if (i == 0) {  // level-1 part: S1[t] = a[t] + 0.5*dx[t]
        float s1 = a_ch[tt][j] + 0.5f * dx_ch[tt][j];
        sig[row * SIGD + j] = (_Float16)(s1 * inv);
      }
    }
    __syncthreads();
  }
}

// ============ K2: f_all = sigmoid(sig @ Wf + b_f), fp16 MFMA ============
__global__ __launch_bounds__(256) void k_fgemm(const _Float16* __restrict__ sig,
                                               const _Float16* __restrict__ Wf16,
                                               const float* __restrict__ bias,
                                               float* __restrict__ f_buf) {
  const int tid = threadIdx.x;
  const int m0 = blockIdx.x * 64;
  const int n0 = blockIdx.y * 128;
  __shared__ __align__(16) ushort_t As[64 * 40];    // [m][k] pad 40
  __shared__ __align__(16) ushort_t Bs[128 * 40];   // [n][k] pad 40
  const uint_t* sig32 = (const uint_t*)sig;
  const uint_t* w32 = (const uint_t*)Wf16;
  f32x4 acc[8];
#pragma unroll
  for (int nt = 0; nt < 8; ++nt) acc[nt] = f32x4{0.f, 0.f, 0.f, 0.f};
  const int lane = tid & 63, w = tid >> 6;
  const int cl = lane & 15, q8 = (lane >> 4) * 8;
  for (int kt = 0; kt < 33; ++kt) {
#pragma unroll
    for (int it = 0; it < 4; ++it) {  // A tile: 64 rows x 16 u32
      int idx = tid + (it << 8);
      int row = idx >> 4, kp = idx & 15;
      uint_t v = sig32[(m0 + row) * 528 + kt * 16 + kp];
      *(uint_t*)&As[row * 40 + kp * 2] = v;
    }
#pragma unroll
    for (int it = 0; it < 8; ++it) {  // B tile: 32 k-rows x 64 u32, transpose to [n][k]
      int idx = tid + (it << 8);
      int kr = idx >> 6, np = idx & 63;
      uint_t v = w32[(kt * 32 + kr) * 256 + (n0 >> 1) + np];
      Bs[(np * 2) * 40 + kr] = (ushort_t)(v & 0xffffu);
      Bs[(np * 2 + 1) * 40 + kr] = (ushort_t)(v >> 16);
    }
    __syncthreads();
    half8 a = *(const half8*)&As[(w * 16 + cl) * 40 + q8];
#pragma unroll
    for (int nt = 0; nt < 8; ++nt) {
      half8 bfr = *(const half8*)&Bs[(nt * 16 + cl) * 40 + q8];
      acc[nt] = __builtin_amdgcn_mfma_f32_16x16x32_f16(a, bfr, acc[nt], 0, 0, 0);
    }
    __syncthreads();
  }
#pragma unroll
  for (int nt = 0; nt < 8; ++nt) {
    int col = n0 + nt * 16 + cl;
    float bf = bias[512 + col];
#pragma unroll
    for (int r = 0; r < 4; ++r) {
      int m = m0 + w * 16 + ((lane >> 4) << 2) + r;  // C/D: col=lane&15, row=quad*4+r
      int t = m & 511, b = m >> 9;
      float z = acc[nt][r] + bf;
      float fv = 1.f / (1.f + __expf(-z));
      f_buf[((t << 6) + b) * 512 + col] = fv;
    }
  }
}

// ============ K3: persistent LSTM scan ============
// 64 WGs, WG g owns units [8g,8g+8). B-fragments (R||Wi cols) live in registers.
// h exchanged through global fp16 double-buffer with agent-scope atomics
// (coherent at LLC across XCDs); per-step arrival counters as the barrier.
__global__ __launch_bounds__(256, 1) void k_scan(const _Float16* __restrict__ R16t,
                                                 const float* __restrict__ bias,
                                                 const float* __restrict__ f_buf,
                                                 const uint_t* __restrict__ x16_32,
                                                 uint_t* hb, uint_t* cnt,
                                                 float* __restrict__ out) {
  const int g = blockIdx.x;
  const int tid = threadIdx.x;
  const int lane = tid & 63, w = tid >> 6;
  const int cl = lane & 15;
  const int q8 = (lane >> 4) * 8;
  const int u0 = g * 8;
  const int up = lane & 7;
  __shared__ __align__(16) ushort_t sm[64 * 296];  // A staging, row stride 296 f16 (148 u32)
  uint_t* sm32 = (uint_t*)sm;

  // ---- preload B fragments into registers: 17 ksteps x 2 ntiles (136 VGPRs) ----
  // cols: [0..7]=i-gate u0+., [8..15]=chat 512+u0+., [16..23]=o 1024+u0+., [24..31]=dummy
  half8 bf[17][2];
#pragma unroll
  for (int nt = 0; nt < 2; ++nt) {
    int c_loc = nt * 16 + cl;
    int ncol;
    if (c_loc < 8) ncol = u0 + c_loc;
    else if (c_loc < 16) ncol = 512 + u0 + (c_loc - 8);
    else if (c_loc < 24) ncol = 1024 + u0 + (c_loc - 16);
    else ncol = 0;
#pragma unroll
    for (int kk = 0; kk < 17; ++kk) {
#pragma unroll
      for (int j = 0; j < 8; ++j)
        bf[kk][nt][j] = R16t[(kk * 32 + q8 + j) * 1536 + ncol];
    }
  }
  float bi = bias[u0 + up];
  float bc = bias[1024 + u0 + up];
  float bo = bias[1536 + u0 + up];
  float c_st[4] = {0.f, 0.f, 0.f, 0.f};
  const int mrow = w * 16 + cl;          // A-frag row = batch
  const bool act = cl < 8;
  const int brow_base = w * 16 + ((lane >> 4) << 2);

#pragma unroll 1
  for (int t = 0; t < T_; ++t) {
    if (t > 0) {
      if (tid == 0) {
        while (__hip_atomic_load(&cnt[t - 1], __ATOMIC_RELAXED, __HIP_MEMORY_SCOPE_AGENT) < G_)
          __builtin_amdgcn_s_sleep(1);
      }
      __syncthreads();
    }
    uint_t* hb_r = hb + ((t & 1) ? 16384 : 0);
    uint_t* hb_w = hb + ((t & 1) ? 0 : 16384);
    f32x4 acc0 = f32x4{0.f, 0.f, 0.f, 0.f};
    f32x4 acc1 = f32x4{0.f, 0.f, 0.f, 0.f};

    // ---- phase 0: stage h k=0..255, 8 MFMA ksteps ----
#pragma unroll
    for (int it = 0; it < 32; ++it) {
      int idx = tid + (it << 8);
      int row = idx >> 7, kp = idx & 127;
      uint_t v = __hip_atomic_load(&hb_r[(row << 8) + kp], __ATOMIC_RELAXED, __HIP_MEMORY_SCOPE_AGENT);
      sm32[row * 148 + kp] = v;
    }
    __syncthreads();
    {
      const ushort_t* ab = &sm[mrow * 296 + q8];
#pragma unroll
      for (int kk = 0; kk < 8; ++kk) {
        half8 a = *(const half8*)(ab + kk * 32);
        acc0 = __builtin_amdgcn_mfma_f32_16x16x32_f16(a, bf[kk][0], acc0, 0, 0, 0);
        acc1 = __builtin_amdgcn_mfma_f32_16x16x32_f16(a, bf[kk][1], acc1, 0, 0, 0);
      }
    }
    __syncthreads();
    // ---- phase 1: stage h k=256..511 + x_t (k=512..543), 9 ksteps ----
#pragma unroll
    for (int it = 0; it < 32; ++it) {
      int idx = tid + (it << 8);
      int row = idx >> 7, kp = idx & 127;
      uint_t v = __hip_atomic_load(&hb_r[(row << 8) + 128 + kp], __ATOMIC_RELAXED, __HIP_MEMORY_SCOPE_AGENT);
      sm32[row * 148 + kp] = v;
    }
#pragma unroll
    for (int it = 0; it < 4; ++it) {
      int idx = tid + (it << 8);
      int row = idx >> 4, xp = idx & 15;
      sm32[row * 148 + 128 + xp] = x16_32[t * 1024 + row * 16 + xp];
    }
    __syncthreads();
    {
      const ushort_t* ab = &sm[mrow * 296 + q8];
#pragma unroll
      for (int kk = 0; kk < 9; ++kk) {
        half8 a = *(const half8*)(ab + kk * 32);
        acc0 = __builtin_amdgcn_mfma_f32_16x16x32_f16(a, bf[8 + kk][0], acc0, 0, 0, 0);
        acc1 = __builtin_amdgcn_mfma_f32_16x16x32_f16(a, bf[8 + kk][1], acc1, 0, 0, 0);
      }
    }
    // ---- epilogue: gates -> c,h.  acc0 cols 0-7 = i, 8-15 = chat; acc1 cols 0-7 = o ----
#pragma unroll
    for (int r = 0; r < 4; ++r) {
      float v0 = acc0[r];
      float pr = __shfl_xor(v0, 8);   // lo lanes receive chat
      int brow = brow_base + r;
      float i_pre = v0 + bi;
      float ch_pre = pr + bc;
      float o_pre = acc1[r] + bo;
      float fv = act ? f_buf[(((t << 6) + brow) << 9) + u0 + up] : 0.f;
      float is = 1.f / (1.f + __expf(-i_pre));
      float ch = 1.f - 2.f / (__expf(2.f * ch_pre) + 1.f);
      float os = 1.f / (1.f + __expf(-o_pre));
      float c = fv * c_st[r] + is * ch;
      c_st[r] = c;
      float h = os * (1.f - 2.f / (__expf(2.f * c) + 1.f));
      ushort_t hu = __builtin_bit_cast(ushort_t, (_Float16)h);
      uint_t nbr = (uint_t)(unsigned)__shfl_xor((int)hu, 1);
      uint_t packed = ((uint_t)hu & 0xffffu) | (nbr << 16);
      if (t < T_ - 1) {
        if (act && !(lane & 1))
          __hip_atomic_store(&hb_w[(brow << 8) + (u0 >> 1) + (up >> 1)], packed,
                             __ATOMIC_RELAXED, __HIP_MEMORY_SCOPE_AGENT);
      } else {
        if (act) out[(brow << 9) + u0 + up] = h;
      }
    }
    // ---- arrive ----
    asm volatile("s_waitcnt vmcnt(0)" ::: "memory");
    __syncthreads();
    if (tid == 0)
      __hip_atomic_fetch_add(&cnt[t], 1u, __ATOMIC_RELEASE, __HIP_MEMORY_SCOPE_AGENT);
  }
}

extern "C" void kernel_launch(void* const* d_in, const int* in_sizes, int n_in,
                              void* d_out, int out_size, void* d_ws, size_t ws_size,
                              hipStream_t stream) {
  const float* x = (const float*)d_in[0];
  const float* ik = (const float*)d_in[1];
  const float* rk = (const float*)d_in[2];
  const float* fk = (const float*)d_in[3];
  const float* bias = (const float*)d_in[4];
  char* ws = (char*)d_ws;
  _Float16* sig = (_Float16*)(ws + SIG_OFF);
  float* f_buf = (float*)(ws + F_OFF);
  float* a_buf = (float*)(ws + A_OFF);
  float* dx_buf = (float*)(ws + DX_OFF);
  _Float16* x16 = (_Float16*)(ws + X16_OFF);
  _Float16* R16t = (_Float16*)(ws + R16_OFF);
  _Float16* Wf16 = (_Float16*)(ws + WF16_OFF);
  uint_t* hb = (uint_t*)(ws + HB_OFF);
  uint_t* cnt = (uint_t*)(ws + CNT_OFF);
  float* out = (float*)d_out;

  hipLaunchKernelGGL(k_prep, dim3(65), dim3(256), 0, stream, x, x16, a_buf, dx_buf, hb, cnt);
  hipLaunchKernelGGL(k_weights, dim3(1344), dim3(256), 0, stream, rk, ik, fk, R16t, Wf16);
  hipLaunchKernelGGL(k_sig, dim3(64), dim3(1024), 0, stream, a_buf, dx_buf, sig);
  hipLaunchKernelGGL(k_fgemm, dim3(512, 4), dim3(256), 0, stream, sig, Wf16, bias, f_buf);
  hipLaunchKernelGGL(k_scan, dim3(G_), dim3(256), 0, stream, R16t, bias, f_buf,
                     (const uint_t*)x16, hb, cnt, out);
}

// Round 2
// 5800.653 us; speedup vs baseline: 1.7184x; 1.7184x over previous
//
#include <hip/hip_runtime.h>

#define B_ 64
#define T_ 512
#define D_ 32
#define U_ 512
#define SIGD 1056
#define G_ 64   // scan workgroups (all co-resident: 64 blocks << 256 CUs)

typedef _Float16 half8 __attribute__((ext_vector_type(8)));
typedef float f32x4 __attribute__((ext_vector_type(4)));
typedef unsigned short ushort_t;
typedef unsigned int uint_t;
typedef unsigned long long ull_t;

// ---- workspace layout (bytes) ----  total ~143 MB
#define SIG_OFF   0ull            // fp16 norm_sigs  [b*512+t][1056]           69,206,016
#define F_OFF     69206016ull     // fp32 f_all      [t][b][u]                 67,108,864
#define A_OFF     136314880ull    // fp32 a = S1[t-1]+.5dx   [b][t][i]          4,194,304
#define DX_OFF    140509184ull    // fp32 dx                 [b][t][i]          4,194,304
#define X16_OFF   144703488ull    // fp16 x          [t][b][i]                  2,097,152
#define R16_OFF   146800640ull    // fp16 [R;Wi]     [k=544][n=1536]            1,671,168
#define WF16_OFF  148471808ull    // fp16 Wf         [k=1056][n=512]            1,081,344
#define HB_OFF    149553152ull    // fp16 h double buffer: 2 x [64][512]          131,072
#define FLG_OFF   149684224ull    // u32 flags [t][64]                            131,072

// ============ K0: dx / a / x16 precompute + zero h/flags ============
__global__ __launch_bounds__(256) void k_prep(const float* __restrict__ x,
                                              _Float16* x16, float* a_buf, float* dx_buf,
                                              uint_t* hb, uint_t* flg) {
  int b = blockIdx.x;
  int tid = threadIdx.x;
  if (b == 64) {  // zero both h buffers (32768 u32) + 32768 flag u32s
    for (int i = tid; i < 65536; i += 256) {
      if (i < 32768) hb[i] = 0u;
      else flg[i - 32768] = 0u;
    }
    return;
  }
  if (tid >= 32) return;
  int i = tid;
  float xprev = x[(b * T_) * D_ + i];
  x16[(0 * B_ + b) * D_ + i] = (_Float16)xprev;
  a_buf[(b * T_) * D_ + i] = 0.f;
  dx_buf[(b * T_) * D_ + i] = 0.f;
  float S1 = 0.f;
  for (int t = 1; t < T_; ++t) {
    float xv = x[(b * T_ + t) * D_ + i];
    float dx = xv - xprev;
    float a = S1 + 0.5f * dx;   // S1 before this increment, + half-dx term
    S1 += dx;
    a_buf[(b * T_ + t) * D_ + i] = a;
    dx_buf[(b * T_ + t) * D_ + i] = dx;
    x16[(t * B_ + b) * D_ + i] = (_Float16)xv;
    xprev = xv;
  }
}

// ============ K0b: weight fp16 conversion ============
__global__ __launch_bounds__(256) void k_weights(const float* __restrict__ rk,
                                                 const float* __restrict__ ik,
                                                 const float* __restrict__ fk,
                                                 _Float16* R16t, _Float16* Wf16) {
  int e = (blockIdx.x * 256 + threadIdx.x) * 4;
  if (e < 835584) {
    const float* src = (e < 786432) ? (rk + e) : (ik + (e - 786432));
#pragma unroll
    for (int j = 0; j < 4; ++j) R16t[e + j] = (_Float16)src[j];
  } else {
    int e2 = e - 835584;  // < 540672
#pragma unroll
    for (int j = 0; j < 4; ++j) Wf16[e2 + j] = (_Float16)fk[e2 + j];
  }
}

// ============ K1: signature stream -> normalized fp16 sig matrix ============
__global__ __launch_bounds__(1024) void k_sig(const float* __restrict__ a_buf,
                                              const float* __restrict__ dx_buf,
                                              _Float16* __restrict__ sig) {
  int b = blockIdx.x;
  int tid = threadIdx.x;
  int i = tid >> 5, j = tid & 31;
  __shared__ float a_ch[32][32];
  __shared__ float dx_ch[32][32];
  float S2 = 0.f;
  for (int t0 = 0; t0 < T_; t0 += 32) {
    a_ch[i][j]  = a_buf[(b * T_ + t0 + i) * D_ + j];
    dx_ch[i][j] = dx_buf[(b * T_ + t0 + i) * D_ + j];
    __syncthreads();
#pragma unroll 4
    for (int tt = 0; tt < 32; ++tt) {
      int t = t0 + tt;
      S2 += a_ch[tt][i] * dx_ch[tt][j];
      float inv = (t == 0) ? 0.f : (1.0f / (float)t);
      int row = b * T_ + t;
      sig[row * SIGD + 32 + i * 32 + j] = (_Float16)(S2 * inv);
      if (i == 0) {
        float s1 = a_ch[tt][j] + 0.5f * dx_ch[tt][j];
        sig[row * SIGD + j] = (_Float16)(s1 * inv);
      }
    }
    __syncthreads();
  }
}

// ============ K2: f_all = sigmoid(sig @ Wf + b_f), fp16 MFMA ============
__global__ __launch_bounds__(256) void k_fgemm(const _Float16* __restrict__ sig,
                                               const _Float16* __restrict__ Wf16,
                                               const float* __restrict__ bias,
                                               float* __restrict__ f_buf) {
  const int tid = threadIdx.x;
  const int m0 = blockIdx.x * 64;
  const int n0 = blockIdx.y * 128;
  __shared__ __align__(16) ushort_t As[64 * 40];
  __shared__ __align__(16) ushort_t Bs[128 * 40];
  const uint_t* sig32 = (const uint_t*)sig;
  const uint_t* w32 = (const uint_t*)Wf16;
  f32x4 acc[8];
#pragma unroll
  for (int nt = 0; nt < 8; ++nt) acc[nt] = f32x4{0.f, 0.f, 0.f, 0.f};
  const int lane = tid & 63, w = tid >> 6;
  const int cl = lane & 15, q8 = (lane >> 4) * 8;
  for (int kt = 0; kt < 33; ++kt) {
#pragma unroll
    for (int it = 0; it < 4; ++it) {
      int idx = tid + (it << 8);
      int row = idx >> 4, kp = idx & 15;
      uint_t v = sig32[(m0 + row) * 528 + kt * 16 + kp];
      *(uint_t*)&As[row * 40 + kp * 2] = v;
    }
#pragma unroll
    for (int it = 0; it < 8; ++it) {
      int idx = tid + (it << 8);
      int kr = idx >> 6, np = idx & 63;
      uint_t v = w32[(kt * 32 + kr) * 256 + (n0 >> 1) + np];
      Bs[(np * 2) * 40 + kr] = (ushort_t)(v & 0xffffu);
      Bs[(np * 2 + 1) * 40 + kr] = (ushort_t)(v >> 16);
    }
    __syncthreads();
    half8 a = *(const half8*)&As[(w * 16 + cl) * 40 + q8];
#pragma unroll
    for (int nt = 0; nt < 8; ++nt) {
      half8 bfr = *(const half8*)&Bs[(nt * 16 + cl) * 40 + q8];
      acc[nt] = __builtin_amdgcn_mfma_f32_16x16x32_f16(a, bfr, acc[nt], 0, 0, 0);
    }
    __syncthreads();
  }
#pragma unroll
  for (int nt = 0; nt < 8; ++nt) {
    int col = n0 + nt * 16 + cl;
    float bf = bias[512 + col];
#pragma unroll
    for (int r = 0; r < 4; ++r) {
      int m = m0 + w * 16 + ((lane >> 4) << 2) + r;
      int t = m & 511, b = m >> 9;
      float z = acc[nt][r] + bf;
      float fv = 1.f / (1.f + __expf(-z));
      f_buf[((t << 6) + b) * 512 + col] = fv;
    }
  }
}

// ============ K3: persistent LSTM scan ============
// Barrier: per-WG flag array flags[t][g] (relaxed sc1 store after vmcnt(0));
// consumers: wave 0 vector-polls all 64 flags, __all() to detect. No RMW,
// no release cache-maintenance, no single-line ping-pong.
__global__ __launch_bounds__(256, 1) void k_scan(const _Float16* __restrict__ R16t,
                                                 const float* __restrict__ bias,
                                                 const float* __restrict__ f_buf,
                                                 const uint_t* __restrict__ x16_32,
                                                 uint_t* hb, uint_t* flg,
                                                 float* __restrict__ out) {
  const int g = blockIdx.x;
  const int tid = threadIdx.x;
  const int lane = tid & 63, w = tid >> 6;
  const int cl = lane & 15;
  const int q8 = (lane >> 4) * 8;
  const int u0 = g * 8;
  const int up = lane & 7;
  __shared__ __align__(16) ushort_t sm[64 * 296];  // A staging, row stride 296 f16
  uint_t* sm32 = (uint_t*)sm;
  ull_t* sm64 = (ull_t*)sm;

  // ---- preload B fragments: 17 ksteps x 2 ntiles (136 VGPRs) ----
  half8 bf[17][2];
#pragma unroll
  for (int nt = 0; nt < 2; ++nt) {
    int c_loc = nt * 16 + cl;
    int ncol;
    if (c_loc < 8) ncol = u0 + c_loc;
    else if (c_loc < 16) ncol = 512 + u0 + (c_loc - 8);
    else if (c_loc < 24) ncol = 1024 + u0 + (c_loc - 16);
    else ncol = 0;
#pragma unroll
    for (int kk = 0; kk < 17; ++kk) {
#pragma unroll
      for (int j = 0; j < 8; ++j)
        bf[kk][nt][j] = R16t[(kk * 32 + q8 + j) * 1536 + ncol];
    }
  }
  float bi = bias[u0 + up];
  float bc = bias[1024 + u0 + up];
  float bo = bias[1536 + u0 + up];
  float c_st[4] = {0.f, 0.f, 0.f, 0.f};
  const int mrow = w * 16 + cl;
  const bool act = cl < 8;
  const int brow_base = w * 16 + ((lane >> 4) << 2);

#pragma unroll 1
  for (int t = 0; t < T_; ++t) {
    // ---- prefetch t-dependent, h-independent data BEFORE the wait ----
    float fpre[4];
#pragma unroll
    for (int r = 0; r < 4; ++r)
      fpre[r] = act ? f_buf[(((t << 6) + brow_base + r) << 9) + u0 + up] : 0.f;
    uint_t xreg[4];
#pragma unroll
    for (int it = 0; it < 4; ++it)
      xreg[it] = x16_32[t * 1024 + tid + (it << 8)];

    // ---- wait for step t-1 h (flag-array barrier, wave 0 polls) ----
    if (t > 0) {
      if (tid < 64) {
        const uint_t* fl = flg + ((t - 1) << 6);
        while (!__all(__hip_atomic_load(&fl[lane], __ATOMIC_RELAXED,
                                        __HIP_MEMORY_SCOPE_AGENT) != 0u))
          __builtin_amdgcn_s_sleep(1);
      }
      __syncthreads();
    }
    uint_t* hb_r = hb + ((t & 1) ? 16384 : 0);
    uint_t* hb_w = hb + ((t & 1) ? 0 : 16384);
    f32x4 acc0 = f32x4{0.f, 0.f, 0.f, 0.f};
    f32x4 acc1 = f32x4{0.f, 0.f, 0.f, 0.f};

    // ---- phase 0: stage h k=0..255 (64-bit agent loads), 8 MFMA ksteps ----
#pragma unroll
    for (int it = 0; it < 16; ++it) {
      int idx = tid + (it << 8);          // 0..4095
      int row = idx >> 6, kp = idx & 63;  // 64 ull per row-half
      ull_t v = __hip_atomic_load((ull_t*)hb_r + (row << 7) + kp,
                                  __ATOMIC_RELAXED, __HIP_MEMORY_SCOPE_AGENT);
      sm64[row * 74 + kp] = v;
    }
    __syncthreads();
    {
      const ushort_t* ab = &sm[mrow * 296 + q8];
#pragma unroll
      for (int kk = 0; kk < 8; ++kk) {
        half8 a = *(const half8*)(ab + kk * 32);
        acc0 = __builtin_amdgcn_mfma_f32_16x16x32_f16(a, bf[kk][0], acc0, 0, 0, 0);
        acc1 = __builtin_amdgcn_mfma_f32_16x16x32_f16(a, bf[kk][1], acc1, 0, 0, 0);
      }
    }
    __syncthreads();
    // ---- phase 1: stage h k=256..511 + x_t (k=512..543), 9 ksteps ----
#pragma unroll
    for (int it = 0; it < 16; ++it) {
      int idx = tid + (it << 8);
      int row = idx >> 6, kp = idx & 63;
      ull_t v = __hip_atomic_load((ull_t*)hb_r + (row << 7) + 64 + kp,
                                  __ATOMIC_RELAXED, __HIP_MEMORY_SCOPE_AGENT);
      sm64[row * 74 + kp] = v;
    }
#pragma unroll
    for (int it = 0; it < 4; ++it) {
      int idx = tid + (it << 8);
      int row = idx >> 4, xp = idx & 15;
      sm32[row * 148 + 128 + xp] = xreg[it];
    }
    __syncthreads();
    {
      const ushort_t* ab = &sm[mrow * 296 + q8];
#pragma unroll
      for (int kk = 0; kk < 9; ++kk) {
        half8 a = *(const half8*)(ab + kk * 32);
        acc0 = __builtin_amdgcn_mfma_f32_16x16x32_f16(a, bf[8 + kk][0], acc0, 0, 0, 0);
        acc1 = __builtin_amdgcn_mfma_f32_16x16x32_f16(a, bf[8 + kk][1], acc1, 0, 0, 0);
      }
    }
    // ---- epilogue: gates -> c,h ----
#pragma unroll
    for (int r = 0; r < 4; ++r) {
      float v0 = acc0[r];
      float pr = __shfl_xor(v0, 8);   // lo lanes receive chat
      int brow = brow_base + r;
      float i_pre = v0 + bi;
      float ch_pre = pr + bc;
      float o_pre = acc1[r] + bo;
      float fv = fpre[r];
      float is = 1.f / (1.f + __expf(-i_pre));
      float ch = 1.f - 2.f / (__expf(2.f * ch_pre) + 1.f);
      float os = 1.f / (1.f + __expf(-o_pre));
      float c = fv * c_st[r] + is * ch;
      c_st[r] = c;
      float h = os * (1.f - 2.f / (__expf(2.f * c) + 1.f));
      ushort_t hu = __builtin_bit_cast(ushort_t, (_Float16)h);
      uint_t nbr = (uint_t)(unsigned)__shfl_xor((int)hu, 1);
      uint_t packed = ((uint_t)hu & 0xffffu) | (nbr << 16);
      if (t < T_ - 1) {
        if (act && !(lane & 1))
          __hip_atomic_store(&hb_w[(brow << 8) + (u0 >> 1) + (up >> 1)], packed,
                             __ATOMIC_RELAXED, __HIP_MEMORY_SCOPE_AGENT);
      } else {
        if (act) out[(brow << 9) + u0 + up] = h;
      }
    }
    // ---- arrive: drain own stores, then set this WG's flag for step t ----
    asm volatile("s_waitcnt vmcnt(0)" ::: "memory");
    __syncthreads();
    if (tid == 0 && t < T_ - 1)
      __hip_atomic_store(&flg[(t << 6) + g], 1u, __ATOMIC_RELAXED,
                         __HIP_MEMORY_SCOPE_AGENT);
  }
}

extern "C" void kernel_launch(void* const* d_in, const int* in_sizes, int n_in,
                              void* d_out, int out_size, void* d_ws, size_t ws_size,
                              hipStream_t stream) {
  const float* x = (const float*)d_in[0];
  const float* ik = (const float*)d_in[1];
  const float* rk = (const float*)d_in[2];
  const float* fk = (const float*)d_in[3];
  const float* bias = (const float*)d_in[4];
  char* ws = (char*)d_ws;
  _Float16* sig = (_Float16*)(ws + SIG_OFF);
  float* f_buf = (float*)(ws + F_OFF);
  float* a_buf = (float*)(ws + A_OFF);
  float* dx_buf = (float*)(ws + DX_OFF);
  _Float16* x16 = (_Float16*)(ws + X16_OFF);
  _Float16* R16t = (_Float16*)(ws + R16_OFF);
  _Float16* Wf16 = (_Float16*)(ws + WF16_OFF);
  uint_t* hb = (uint_t*)(ws + HB_OFF);
  uint_t* flg = (uint_t*)(ws + FLG_OFF);
  float* out = (float*)d_out;

  hipLaunchKernelGGL(k_prep, dim3(65), dim3(256), 0, stream, x, x16, a_buf, dx_buf, hb, flg);
  hipLaunchKernelGGL(k_weights, dim3(1344), dim3(256), 0, stream, rk, ik, fk, R16t, Wf16);
  hipLaunchKernelGGL(k_sig, dim3(64), dim3(1024), 0, stream, a_buf, dx_buf, sig);
  hipLaunchKernelGGL(k_fgemm, dim3(512, 4), dim3(256), 0, stream, sig, Wf16, bias, f_buf);
  hipLaunchKernelGGL(k_scan, dim3(G_), dim3(256), 0, stream, R16t, bias, f_buf,
                     (const uint_t*)x16, hb, flg, out);
}

// Round 3
// 3750.404 us; speedup vs baseline: 2.6577x; 1.5467x over previous
//
#include <hip/hip_runtime.h>

#define B_ 64
#define T_ 512
#define D_ 32
#define U_ 512
#define SIGD 1056
#define G_ 64   // scan workgroups (64 WGs x 4 waves = 256 waves, all co-resident)

typedef _Float16 half8 __attribute__((ext_vector_type(8)));
typedef float f32x4 __attribute__((ext_vector_type(4)));
typedef unsigned short ushort_t;
typedef unsigned int uint_t;
typedef unsigned long long ull_t;

// ---- workspace layout (bytes) ----
#define SIG_OFF   0ull            // fp16 norm_sigs  [b*512+t][1056]           69,206,016
#define F_OFF     69206016ull     // fp16 f_all      [t][b][u]                 33,554,432
#define FLG_OFF   102760448ull    // u32 flags [t][256]                           524,288
#define A_OFF     136314880ull    // fp32 a = S1[t-1]+.5dx   [b][t][i]          4,194,304
#define DX_OFF    140509184ull    // fp32 dx                 [b][t][i]          4,194,304
#define X16_OFF   144703488ull    // fp16 x          [t][b][i]                  2,097,152
#define R16_OFF   146800640ull    // fp16 [R;Wi]     [k=544][n=1536]            1,671,168
#define WF16_OFF  148471808ull    // fp16 Wf         [k=1056][n=512]            1,081,344
#define HB_OFF    149553152ull    // fp16 h double buffer: 2 x [64][512]          131,072

// ============ K0: dx / a / x16 precompute + zero h/flags ============
__global__ __launch_bounds__(256) void k_prep(const float* __restrict__ x,
                                              _Float16* x16, float* a_buf, float* dx_buf,
                                              uint_t* hb, uint_t* flg) {
  int b = blockIdx.x;
  int tid = threadIdx.x;
  if (b >= 64) {  // blocks 64..67: zero hb (32768 u32) + flg (131072 u32)
    int zb = b - 64;
    for (int i = tid; i < 40960; i += 256) {
      int idx = zb * 40960 + i;
      if (idx < 32768) hb[idx] = 0u;
      else if (idx < 163840) flg[idx - 32768] = 0u;
    }
    return;
  }
  if (tid >= 32) return;
  int i = tid;
  float xprev = x[(b * T_) * D_ + i];
  x16[(0 * B_ + b) * D_ + i] = (_Float16)xprev;
  a_buf[(b * T_) * D_ + i] = 0.f;
  dx_buf[(b * T_) * D_ + i] = 0.f;
  float S1 = 0.f;
  for (int t = 1; t < T_; ++t) {
    float xv = x[(b * T_ + t) * D_ + i];
    float dx = xv - xprev;
    float a = S1 + 0.5f * dx;
    S1 += dx;
    a_buf[(b * T_ + t) * D_ + i] = a;
    dx_buf[(b * T_ + t) * D_ + i] = dx;
    x16[(t * B_ + b) * D_ + i] = (_Float16)xv;
    xprev = xv;
  }
}

// ============ K0b: weight fp16 conversion ============
__global__ __launch_bounds__(256) void k_weights(const float* __restrict__ rk,
                                                 const float* __restrict__ ik,
                                                 const float* __restrict__ fk,
                                                 _Float16* R16t, _Float16* Wf16) {
  int e = (blockIdx.x * 256 + threadIdx.x) * 4;
  if (e < 835584) {
    const float* src = (e < 786432) ? (rk + e) : (ik + (e - 786432));
#pragma unroll
    for (int j = 0; j < 4; ++j) R16t[e + j] = (_Float16)src[j];
  } else {
    int e2 = e - 835584;  // < 540672
#pragma unroll
    for (int j = 0; j < 4; ++j) Wf16[e2 + j] = (_Float16)fk[e2 + j];
  }
}

// ============ K1: signature stream -> normalized fp16 sig matrix ============
__global__ __launch_bounds__(1024) void k_sig(const float* __restrict__ a_buf,
                                              const float* __restrict__ dx_buf,
                                              _Float16* __restrict__ sig) {
  int b = blockIdx.x;
  int tid = threadIdx.x;
  int i = tid >> 5, j = tid & 31;
  __shared__ float a_ch[32][32];
  __shared__ float dx_ch[32][32];
  float S2 = 0.f;
  for (int t0 = 0; t0 < T_; t0 += 32) {
    a_ch[i][j]  = a_buf[(b * T_ + t0 + i) * D_ + j];
    dx_ch[i][j] = dx_buf[(b * T_ + t0 + i) * D_ + j];
    __syncthreads();
#pragma unroll 4
    for (int tt = 0; tt < 32; ++tt) {
      int t = t0 + tt;
      S2 += a_ch[tt][i] * dx_ch[tt][j];
      float inv = (t == 0) ? 0.f : (1.0f / (float)t);
      int row = b * T_ + t;
      sig[row * SIGD + 32 + i * 32 + j] = (_Float16)(S2 * inv);
      if (i == 0) {
        float s1 = a_ch[tt][j] + 0.5f * dx_ch[tt][j];
        sig[row * SIGD + j] = (_Float16)(s1 * inv);
      }
    }
    __syncthreads();
  }
}

// ============ K2: f_all = sigmoid(sig @ Wf + b_f), fp16 MFMA, fp16 out ============
__global__ __launch_bounds__(256) void k_fgemm(const _Float16* __restrict__ sig,
                                               const _Float16* __restrict__ Wf16,
                                               const float* __restrict__ bias,
                                               _Float16* __restrict__ f_buf) {
  const int tid = threadIdx.x;
  const int m0 = blockIdx.x * 64;
  const int n0 = blockIdx.y * 128;
  __shared__ __align__(16) ushort_t As[64 * 40];
  __shared__ __align__(16) ushort_t Bs[128 * 40];
  const uint_t* sig32 = (const uint_t*)sig;
  const uint_t* w32 = (const uint_t*)Wf16;
  f32x4 acc[8];
#pragma unroll
  for (int nt = 0; nt < 8; ++nt) acc[nt] = f32x4{0.f, 0.f, 0.f, 0.f};
  const int lane = tid & 63, w = tid >> 6;
  const int cl = lane & 15, q8 = (lane >> 4) * 8;
  for (int kt = 0; kt < 33; ++kt) {
#pragma unroll
    for (int it = 0; it < 4; ++it) {
      int idx = tid + (it << 8);
      int row = idx >> 4, kp = idx & 15;
      uint_t v = sig32[(m0 + row) * 528 + kt * 16 + kp];
      *(uint_t*)&As[row * 40 + kp * 2] = v;
    }
#pragma unroll
    for (int it = 0; it < 8; ++it) {
      int idx = tid + (it << 8);
      int kr = idx >> 6, np = idx & 63;
      uint_t v = w32[(kt * 32 + kr) * 256 + (n0 >> 1) + np];
      Bs[(np * 2) * 40 + kr] = (ushort_t)(v & 0xffffu);
      Bs[(np * 2 + 1) * 40 + kr] = (ushort_t)(v >> 16);
    }
    __syncthreads();
    half8 a = *(const half8*)&As[(w * 16 + cl) * 40 + q8];
#pragma unroll
    for (int nt = 0; nt < 8; ++nt) {
      half8 bfr = *(const half8*)&Bs[(nt * 16 + cl) * 40 + q8];
      acc[nt] = __builtin_amdgcn_mfma_f32_16x16x32_f16(a, bfr, acc[nt], 0, 0, 0);
    }
    __syncthreads();
  }
#pragma unroll
  for (int nt = 0; nt < 8; ++nt) {
    int col = n0 + nt * 16 + cl;
    float bf = bias[512 + col];
#pragma unroll
    for (int r = 0; r < 4; ++r) {
      int m = m0 + w * 16 + ((lane >> 4) << 2) + r;
      int t = m & 511, b = m >> 9;
      float z = acc[nt][r] + bf;
      float fv = 1.f / (1.f + __expf(-z));
      f_buf[((t << 6) + b) * 512 + col] = (_Float16)fv;
    }
  }
}

// ============ K3: persistent LSTM scan — per-wave sync-free ============
// Each (row,k) of h is consumed by exactly one lane -> A-frags load DIRECTLY
// from global (agent-scope 8B atomics), no LDS, no __syncthreads anywhere.
// 256 per-wave flags; each wave: poll -> load A -> 34 MFMA -> epilogue ->
// vmcnt(0) -> publish flag.
__global__ __launch_bounds__(256, 1) void k_scan(const _Float16* __restrict__ R16t,
                                                 const float* __restrict__ bias,
                                                 const _Float16* __restrict__ f16,
                                                 const _Float16* __restrict__ x16,
                                                 uint_t* hb, uint_t* flg,
                                                 float* __restrict__ out) {
  const int g = blockIdx.x;
  const int tid = threadIdx.x;
  const int lane = tid & 63, w = tid >> 6;
  const int wid = (g << 2) | w;         // global wave id 0..255
  const int cl = lane & 15;
  const int q8 = (lane >> 4) * 8;
  const int u0 = g * 8;
  const int up = lane & 7;

  // ---- preload B fragments: 17 ksteps x 2 ntiles (136 VGPRs) ----
  half8 bf[17][2];
#pragma unroll
  for (int nt = 0; nt < 2; ++nt) {
    int c_loc = nt * 16 + cl;
    int ncol;
    if (c_loc < 8) ncol = u0 + c_loc;
    else if (c_loc < 16) ncol = 512 + u0 + (c_loc - 8);
    else if (c_loc < 24) ncol = 1024 + u0 + (c_loc - 16);
    else ncol = 0;
#pragma unroll
    for (int kk = 0; kk < 17; ++kk) {
#pragma unroll
      for (int j = 0; j < 8; ++j)
        bf[kk][nt][j] = R16t[(kk * 32 + q8 + j) * 1536 + ncol];
    }
  }
  float bi = bias[u0 + up];
  float bc = bias[1024 + u0 + up];
  float bo = bias[1536 + u0 + up];
  float c_st[4] = {0.f, 0.f, 0.f, 0.f};
  const int mrow = w * 16 + cl;         // A-frag row = batch
  const bool act = cl < 8;
  const int brow_base = w * 16 + ((lane >> 4) << 2);

#pragma unroll 1
  for (int t = 0; t < T_; ++t) {
    // ---- prefetch t-dependent, h-independent data BEFORE the wait ----
    float fpre[4];
#pragma unroll
    for (int r = 0; r < 4; ++r)
      fpre[r] = act ? (float)f16[(((t << 6) + brow_base + r) << 9) + u0 + up] : 0.f;
    half8 xa = *(const half8*)(x16 + ((t * 64 + mrow) * 32 + q8));

    // ---- wait for step t-1: every wave polls all 256 per-wave flags ----
    if (t > 0) {
      const uint_t* fl = flg + ((t - 1) << 8);
      for (;;) {
        uint_t v0 = __hip_atomic_load(&fl[lane * 4 + 0], __ATOMIC_RELAXED, __HIP_MEMORY_SCOPE_AGENT);
        uint_t v1 = __hip_atomic_load(&fl[lane * 4 + 1], __ATOMIC_RELAXED, __HIP_MEMORY_SCOPE_AGENT);
        uint_t v2 = __hip_atomic_load(&fl[lane * 4 + 2], __ATOMIC_RELAXED, __HIP_MEMORY_SCOPE_AGENT);
        uint_t v3 = __hip_atomic_load(&fl[lane * 4 + 3], __ATOMIC_RELAXED, __HIP_MEMORY_SCOPE_AGENT);
        if (__all((v0 & v1 & v2 & v3) != 0u)) break;
        __builtin_amdgcn_s_sleep(1);
      }
    }
    const ull_t* hb_r = (const ull_t*)(hb + ((t & 1) ? 16384 : 0));
    uint_t* hb_w = hb + ((t & 1) ? 0 : 16384);

    // ---- load A-fragments directly global -> VGPR (agent-scope) ----
    half8 a[17];
#pragma unroll
    for (int kk = 0; kk < 16; ++kk) {
      const ull_t* p = hb_r + ((mrow * 512 + kk * 32 + q8) >> 2);
      ull_t lo = __hip_atomic_load(p, __ATOMIC_RELAXED, __HIP_MEMORY_SCOPE_AGENT);
      ull_t hi = __hip_atomic_load(p + 1, __ATOMIC_RELAXED, __HIP_MEMORY_SCOPE_AGENT);
      union { ull_t u[2]; half8 h; } cv;
      cv.u[0] = lo; cv.u[1] = hi;
      a[kk] = cv.h;
    }
    a[16] = xa;

    // ---- 34 MFMAs ----
    f32x4 acc0 = f32x4{0.f, 0.f, 0.f, 0.f};
    f32x4 acc1 = f32x4{0.f, 0.f, 0.f, 0.f};
#pragma unroll
    for (int kk = 0; kk < 17; ++kk) {
      acc0 = __builtin_amdgcn_mfma_f32_16x16x32_f16(a[kk], bf[kk][0], acc0, 0, 0, 0);
      acc1 = __builtin_amdgcn_mfma_f32_16x16x32_f16(a[kk], bf[kk][1], acc1, 0, 0, 0);
    }

    // ---- epilogue: gates -> c,h ----
#pragma unroll
    for (int r = 0; r < 4; ++r) {
      float v0 = acc0[r];
      float pr = __shfl_xor(v0, 8);   // lo lanes receive chat
      int brow = brow_base + r;
      float i_pre = v0 + bi;
      float ch_pre = pr + bc;
      float o_pre = acc1[r] + bo;
      float fv = fpre[r];
      float is = 1.f / (1.f + __expf(-i_pre));
      float ch = 1.f - 2.f / (__expf(2.f * ch_pre) + 1.f);
      float os = 1.f / (1.f + __expf(-o_pre));
      float c = fv * c_st[r] + is * ch;
      c_st[r] = c;
      float h = os * (1.f - 2.f / (__expf(2.f * c) + 1.f));
      ushort_t hu = __builtin_bit_cast(ushort_t, (_Float16)h);
      uint_t nbr = (uint_t)(unsigned)__shfl_xor((int)hu, 1);
      uint_t packed = ((uint_t)hu & 0xffffu) | (nbr << 16);
      if (t < T_ - 1) {
        if (act && !(lane & 1))
          __hip_atomic_store(&hb_w[(brow << 8) + (u0 >> 1) + (up >> 1)], packed,
                             __ATOMIC_RELAXED, __HIP_MEMORY_SCOPE_AGENT);
      } else {
        if (act) out[(brow << 9) + u0 + up] = h;
      }
    }
    // ---- drain own stores, publish this wave's flag ----
    asm volatile("s_waitcnt vmcnt(0)" ::: "memory");
    if (lane == 0 && t < T_ - 1)
      __hip_atomic_store(&flg[(t << 8) + wid], 1u, __ATOMIC_RELAXED,
                         __HIP_MEMORY_SCOPE_AGENT);
  }
}

extern "C" void kernel_launch(void* const* d_in, const int* in_sizes, int n_in,
                              void* d_out, int out_size, void* d_ws, size_t ws_size,
                              hipStream_t stream) {
  const float* x = (const float*)d_in[0];
  const float* ik = (const float*)d_in[1];
  const float* rk = (const float*)d_in[2];
  const float* fk = (const float*)d_in[3];
  const float* bias = (const float*)d_in[4];
  char* ws = (char*)d_ws;
  _Float16* sig = (_Float16*)(ws + SIG_OFF);
  _Float16* f_buf = (_Float16*)(ws + F_OFF);
  uint_t* flg = (uint_t*)(ws + FLG_OFF);
  float* a_buf = (float*)(ws + A_OFF);
  float* dx_buf = (float*)(ws + DX_OFF);
  _Float16* x16 = (_Float16*)(ws + X16_OFF);
  _Float16* R16t = (_Float16*)(ws + R16_OFF);
  _Float16* Wf16 = (_Float16*)(ws + WF16_OFF);
  uint_t* hb = (uint_t*)(ws + HB_OFF);
  float* out = (float*)d_out;

  hipLaunchKernelGGL(k_prep, dim3(68), dim3(256), 0, stream, x, x16, a_buf, dx_buf, hb, flg);
  hipLaunchKernelGGL(k_weights, dim3(1344), dim3(256), 0, stream, rk, ik, fk, R16t, Wf16);
  hipLaunchKernelGGL(k_sig, dim3(64), dim3(1024), 0, stream, a_buf, dx_buf, sig);
  hipLaunchKernelGGL(k_fgemm, dim3(512, 4), dim3(256), 0, stream, sig, Wf16, bias, f_buf);
  hipLaunchKernelGGL(k_scan, dim3(G_), dim3(256), 0, stream, R16t, bias, f_buf,
                     x16, hb, flg, out);
}

// Round 6
// 3479.787 us; speedup vs baseline: 2.8644x; 1.0778x over previous
//
#include <hip/hip_runtime.h>

#define B_ 64
#define T_ 512
#define D_ 32
#define U_ 512
#define SIGD 1056

typedef _Float16 half8 __attribute__((ext_vector_type(8)));
typedef float f32x4 __attribute__((ext_vector_type(4)));
typedef unsigned short ushort_t;
typedef unsigned int uint_t;
typedef unsigned long long ull_t;

// ---- workspace layout (bytes) ----
#define SIG_OFF   0ull            // fp16 norm_sigs  [b*512+t][1056]           69,206,016
#define F_OFF     69206016ull     // fp16 f_all      [t][u][b]                 33,554,432
#define FLG_OFF   102760448ull    // u32 flags [(t*8+G)*32 + wave]                524,288
#define A_OFF     136314880ull    // fp32 a          [b][t][i]                  4,194,304
#define DX_OFF    140509184ull    // fp32 dx         [b][t][i]                  4,194,304
#define X16_OFF   144703488ull    // fp16 x          [t][b][i]                  2,097,152
#define R16_OFF   146800640ull    // fp16 [R;Wi]     [k=544][n=1536]            1,671,168
#define WF16_OFF  148471808ull    // fp16 Wf         [k=1056][n=512]            1,081,344
#define HB_OFF    149553152ull    // fp16 h double buffer: 2 x [64][512]          131,072

// ============ K0: dx / a / x16 precompute + zero hb/flg ============
__global__ __launch_bounds__(256) void k_prep(const float* __restrict__ x,
                                              _Float16* x16, float* a_buf, float* dx_buf,
                                              uint_t* hb, uint_t* flg) {
  int b = blockIdx.x;
  int tid = threadIdx.x;
  if (b >= 64) {  // blocks 64..67: zero hb(32768 u32) + flg(131072 u32)
    for (int gi = (b - 64) * 256 + tid; gi < 163840; gi += 1024) {
      if (gi < 32768) hb[gi] = 0u;
      else flg[gi - 32768] = 0u;
    }
    return;
  }
  if (tid >= 32) return;
  int i = tid;
  float xprev = x[(b * T_) * D_ + i];
  x16[(0 * B_ + b) * D_ + i] = (_Float16)xprev;
  a_buf[(b * T_) * D_ + i] = 0.f;
  dx_buf[(b * T_) * D_ + i] = 0.f;
  float S1 = 0.f;
  for (int t = 1; t < T_; ++t) {
    float xv = x[(b * T_ + t) * D_ + i];
    float dx = xv - xprev;
    float a = S1 + 0.5f * dx;
    S1 += dx;
    a_buf[(b * T_ + t) * D_ + i] = a;
    dx_buf[(b * T_ + t) * D_ + i] = dx;
    x16[(t * B_ + b) * D_ + i] = (_Float16)xv;
    xprev = xv;
  }
}

// ============ K0b: weight fp16 conversion ============
__global__ __launch_bounds__(256) void k_weights(const float* __restrict__ rk,
                                                 const float* __restrict__ ik,
                                                 const float* __restrict__ fk,
                                                 _Float16* R16t, _Float16* Wf16) {
  int e = (blockIdx.x * 256 + threadIdx.x) * 4;
  if (e < 835584) {
    const float* src = (e < 786432) ? (rk + e) : (ik + (e - 786432));
#pragma unroll
    for (int j = 0; j < 4; ++j) R16t[e + j] = (_Float16)src[j];
  } else {
    int e2 = e - 835584;  // < 540672
#pragma unroll
    for (int j = 0; j < 4; ++j) Wf16[e2 + j] = (_Float16)fk[e2 + j];
  }
}

// ============ K1: signature stream -> normalized fp16 sig matrix ============
__global__ __launch_bounds__(1024) void k_sig(const float* __restrict__ a_buf,
                                              const float* __restrict__ dx_buf,
                                              _Float16* __restrict__ sig) {
  int b = blockIdx.x;
  int tid = threadIdx.x;
  int i = tid >> 5, j = tid & 31;
  __shared__ float a_ch[32][32];
  __shared__ float dx_ch[32][32];
  float S2 = 0.f;
  for (int t0 = 0; t0 < T_; t0 += 32) {
    a_ch[i][j]  = a_buf[(b * T_ + t0 + i) * D_ + j];
    dx_ch[i][j] = dx_buf[(b * T_ + t0 + i) * D_ + j];
    __syncthreads();
#pragma unroll 4
    for (int tt = 0; tt < 32; ++tt) {
      int t = t0 + tt;
      S2 += a_ch[tt][i] * dx_ch[tt][j];
      float inv = (t == 0) ? 0.f : (1.0f / (float)t);
      int row = b * T_ + t;
      sig[row * SIGD + 32 + i * 32 + j] = (_Float16)(S2 * inv);
      if (i == 0) {
        float s1 = a_ch[tt][j] + 0.5f * dx_ch[tt][j];
        sig[row * SIGD + j] = (_Float16)(s1 * inv);
      }
    }
    __syncthreads();
  }
}

// ============ K2: f_all = sigmoid(sig @ Wf + b_f), fp16 MFMA, out [t][u][b] ============
__global__ __launch_bounds__(256) void k_fgemm(const _Float16* __restrict__ sig,
                                               const _Float16* __restrict__ Wf16,
                                               const float* __restrict__ bias,
                                               _Float16* __restrict__ f_buf) {
  const int tid = threadIdx.x;
  const int m0 = blockIdx.x * 64;
  const int n0 = blockIdx.y * 128;
  __shared__ __align__(16) ushort_t As[64 * 40];
  __shared__ __align__(16) ushort_t Bs[128 * 40];
  const uint_t* sig32 = (const uint_t*)sig;
  const uint_t* w32 = (const uint_t*)Wf16;
  f32x4 acc[8];
#pragma unroll
  for (int nt = 0; nt < 8; ++nt) acc[nt] = f32x4{0.f, 0.f, 0.f, 0.f};
  const int lane = tid & 63, w = tid >> 6;
  const int cl = lane & 15, q8 = (lane >> 4) * 8;
  for (int kt = 0; kt < 33; ++kt) {
#pragma unroll
    for (int it = 0; it < 4; ++it) {
      int idx = tid + (it << 8);
      int row = idx >> 4, kp = idx & 15;
      uint_t v = sig32[(m0 + row) * 528 + kt * 16 + kp];
      *(uint_t*)&As[row * 40 + kp * 2] = v;
    }
#pragma unroll
    for (int it = 0; it < 8; ++it) {
      int idx = tid + (it << 8);
      int kr = idx >> 6, np = idx & 63;
      uint_t v = w32[(kt * 32 + kr) * 256 + (n0 >> 1) + np];
      Bs[(np * 2) * 40 + kr] = (ushort_t)(v & 0xffffu);
      Bs[(np * 2 + 1) * 40 + kr] = (ushort_t)(v >> 16);
    }
    __syncthreads();
    half8 a = *(const half8*)&As[(w * 16 + cl) * 40 + q8];
#pragma unroll
    for (int nt = 0; nt < 8; ++nt) {
      half8 bfr = *(const half8*)&Bs[(nt * 16 + cl) * 40 + q8];
      acc[nt] = __builtin_amdgcn_mfma_f32_16x16x32_f16(a, bfr, acc[nt], 0, 0, 0);
    }
    __syncthreads();
  }
#pragma unroll
  for (int nt = 0; nt < 8; ++nt) {
    int col = n0 + nt * 16 + cl;
    float bf = bias[512 + col];
#pragma unroll
    for (int r = 0; r < 4; ++r) {
      int m = m0 + w * 16 + ((lane >> 4) << 2) + r;
      int t = m & 511, b = m >> 9;
      float z = acc[nt][r] + bf;
      float fv = 1.f / (1.f + __expf(-z));
      f_buf[(t * 512 + col) * 64 + b] = (_Float16)fv;
    }
  }
}

// ============ K3: batch-partitioned persistent LSTM scan ============
// 64 blocks = 8 independent groups (G = bid&7). Group G owns batches
// 8G..8G+8; its 8 blocks x 4 waves each own 16 units with i/c/o B-frags
// register-resident (204 VGPRs). h exchange only WITHIN the group, via
// agent-scope relaxed atomics (R3-proven). Per-WAVE flags: no __syncthreads
// anywhere in the loop; each wave publishes after draining its own stores
// and polls its group's 32 producer-wave flags with one vector load.
__global__ __launch_bounds__(256, 1) void k_scan(const _Float16* __restrict__ R16t,
                                                 const float* __restrict__ bias,
                                                 const _Float16* __restrict__ f16,
                                                 const _Float16* __restrict__ x16,
                                                 uint_t* hb, uint_t* flg,
                                                 float* __restrict__ out) {
  const int tid = threadIdx.x;
  const int bid = blockIdx.x;         // 0..63
  const int G = bid & 7;              // group (batch tile)
  const int mj = bid >> 3;            // member block 0..7
  const int lane = tid & 63, w = tid >> 6;
  const int cl = lane & 15, quad = lane >> 4, q8 = quad * 8;
  const int widx = (mj << 2) | w;     // producer-wave index in group, 0..31
  const int u0 = widx * 16;           // unit tile base
  const int u = u0 + cl;              // this lane's unit
  const int b0 = G * 8;               // batch base
  const int arow = b0 + (cl & 7);     // A-frag batch row (rows 8..15 duplicate)

  // B fragments: 3 gates (i,c,o) x 17 ksteps = 204 VGPRs
  half8 bfr[3][17];
#pragma unroll
  for (int g3 = 0; g3 < 3; ++g3)
#pragma unroll
    for (int kk = 0; kk < 17; ++kk)
#pragma unroll
      for (int jj = 0; jj < 8; ++jj)
        bfr[g3][kk][jj] = R16t[(kk * 32 + q8 + jj) * 1536 + g3 * 512 + u];

  const float bi = bias[u];
  const float bc = bias[1024 + u];
  const float bo = bias[1536 + u];
  float c_st[4] = {0.f, 0.f, 0.f, 0.f};

#pragma unroll 1
  for (int t = 0; t < T_; ++t) {
    // ---- prefetch t-dependent, h-independent data BEFORE the wait ----
    float fpre[4];
    {
      union { ull_t q; _Float16 h[4]; } fu;
      fu.q = *(const ull_t*)(f16 + ((t * 512 + u) * 64 + b0 + (quad & 1) * 4));
#pragma unroll
      for (int r = 0; r < 4; ++r) fpre[r] = (float)fu.h[r];
    }
    half8 xa = *(const half8*)(x16 + ((t * 64 + arow) * 32 + q8));

    // ---- wait for step t-1: poll this group's 32 producer-wave flags ----
    if (t > 0) {
      const uint_t* fp = flg + (((t - 1) * 8 + G) << 5) + (lane & 31);
      for (;;) {
        uint_t v = 1u;
        if (lane < 32)
          v = __hip_atomic_load(fp, __ATOMIC_RELAXED, __HIP_MEMORY_SCOPE_AGENT);
        if (__all(v != 0u)) break;
        __builtin_amdgcn_s_sleep(1);
      }
    }
    const ull_t* h64 = (const ull_t*)(hb + ((t & 1) ? 16384 : 0));
    uint_t* hb_w32 = hb + ((t & 1) ? 0 : 16384);

    // ---- gather A fragments: own group's 8 batch rows (agent atomics) ----
    half8 a[17];
#pragma unroll
    for (int kk = 0; kk < 16; ++kk) {
      int i64 = (arow << 7) + (kk << 3) + (q8 >> 2);
      ull_t lo = __hip_atomic_load(&h64[i64], __ATOMIC_RELAXED, __HIP_MEMORY_SCOPE_AGENT);
      ull_t hi = __hip_atomic_load(&h64[i64 + 1], __ATOMIC_RELAXED, __HIP_MEMORY_SCOPE_AGENT);
      union { ull_t q[2]; half8 h; } cv;
      cv.q[0] = lo; cv.q[1] = hi;
      a[kk] = cv.h;
    }
    a[16] = xa;

    // ---- 51 MFMAs: i, c, o ----
    f32x4 ai = f32x4{0.f, 0.f, 0.f, 0.f};
    f32x4 ac = f32x4{0.f, 0.f, 0.f, 0.f};
    f32x4 ao = f32x4{0.f, 0.f, 0.f, 0.f};
#pragma unroll
    for (int kk = 0; kk < 17; ++kk) {
      ai = __builtin_amdgcn_mfma_f32_16x16x32_f16(a[kk], bfr[0][kk], ai, 0, 0, 0);
      ac = __builtin_amdgcn_mfma_f32_16x16x32_f16(a[kk], bfr[1][kk], ac, 0, 0, 0);
      ao = __builtin_amdgcn_mfma_f32_16x16x32_f16(a[kk], bfr[2][kk], ao, 0, 0, 0);
    }

    // ---- epilogue: gates -> c,h (rows brow<8 are the real batches) ----
#pragma unroll
    for (int r = 0; r < 4; ++r) {
      int brow = (quad << 2) + r;   // local batch row 0..15, valid < 8
      float iv = 1.f / (1.f + __expf(-(ai[r] + bi)));
      float cv = 1.f - 2.f / (__expf(2.f * (ac[r] + bc)) + 1.f);
      float ov = 1.f / (1.f + __expf(-(ao[r] + bo)));
      float c = fpre[r] * c_st[r] + iv * cv;
      c_st[r] = c;
      float h = ov * (1.f - 2.f / (__expf(2.f * c) + 1.f));
      if (t < T_ - 1) {
        ushort_t hu = __builtin_bit_cast(ushort_t, (_Float16)h);
        uint_t nbr = (uint_t)(unsigned)__shfl_xor((int)hu, 1);
        uint_t packed = ((uint_t)hu & 0xffffu) | (nbr << 16);
        if (brow < 8 && !(cl & 1)) {
          int hidx = ((b0 + brow) << 8) + ((u0 + cl) >> 1);  // dword index
          __hip_atomic_store(&hb_w32[hidx], packed, __ATOMIC_RELAXED,
                             __HIP_MEMORY_SCOPE_AGENT);
        }
      } else {
        if (brow < 8) out[((b0 + brow) << 9) + u] = h;
      }
    }
    // ---- drain own stores, publish this wave's flag ----
    asm volatile("s_waitcnt vmcnt(0)" ::: "memory");
    if (lane == 0 && t < T_ - 1)
      __hip_atomic_store(&flg[((t * 8 + G) << 5) + widx], 1u, __ATOMIC_RELAXED,
                         __HIP_MEMORY_SCOPE_AGENT);
  }
}

extern "C" void kernel_launch(void* const* d_in, const int* in_sizes, int n_in,
                              void* d_out, int out_size, void* d_ws, size_t ws_size,
                              hipStream_t stream) {
  const float* x = (const float*)d_in[0];
  const float* ik = (const float*)d_in[1];
  const float* rk = (const float*)d_in[2];
  const float* fk = (const float*)d_in[3];
  const float* bias = (const float*)d_in[4];
  char* ws = (char*)d_ws;
  _Float16* sig = (_Float16*)(ws + SIG_OFF);
  _Float16* f_buf = (_Float16*)(ws + F_OFF);
  uint_t* flg = (uint_t*)(ws + FLG_OFF);
  float* a_buf = (float*)(ws + A_OFF);
  float* dx_buf = (float*)(ws + DX_OFF);
  _Float16* x16 = (_Float16*)(ws + X16_OFF);
  _Float16* R16t = (_Float16*)(ws + R16_OFF);
  _Float16* Wf16 = (_Float16*)(ws + WF16_OFF);
  uint_t* hb = (uint_t*)(ws + HB_OFF);
  float* out = (float*)d_out;

  hipLaunchKernelGGL(k_prep, dim3(68), dim3(256), 0, stream, x, x16, a_buf, dx_buf, hb, flg);
  hipLaunchKernelGGL(k_weights, dim3(1344), dim3(256), 0, stream, rk, ik, fk, R16t, Wf16);
  hipLaunchKernelGGL(k_sig, dim3(64), dim3(1024), 0, stream, a_buf, dx_buf, sig);
  hipLaunchKernelGGL(k_fgemm, dim3(512, 4), dim3(256), 0, stream, sig, Wf16, bias, f_buf);
  hipLaunchKernelGGL(k_scan, dim3(64), dim3(256), 0, stream, R16t, bias, f_buf,
                     x16, hb, flg, out);
}